// Round 1
// baseline (1391.141 us; speedup 1.0000x reference)
//
#include <hip/hip_runtime.h>

#define BATCH 8
#define CHAN 64
#define HH 256
#define WW 256
#define BN_EPS 1e-5f

// ws layout (floats):
// [0..63] sum, [64..127] sumsq, [128..191] a (scale), [192..255] b (shift),
// [256..298] coeffs: K[25], fx[9], fy[9]
// y buffer at float offset 512 (8*64*256*256 floats = 128 Mi floats)
#define WS_SUM 0
#define WS_SUMSQ 64
#define WS_A 128
#define WS_B 192
#define WS_COEF 256
#define WS_Y 512

__global__ void init_stats(float* ws) {
    int t = threadIdx.x;
    if (t < 128) ws[t] = 0.f;
}

// Conv 3x3 (zero pad 1, cross-correlation) + bias, write y, accumulate per-channel sum/sumsq.
// Block: 256 threads = 4 waves. Tile: 64 wide x 4 high, all 64 output channels.
// Wave w handles co in [16w, 16w+16). Thread: 4 consecutive-w pixels x 16 co.
__global__ __launch_bounds__(256) void conv_bn_stats(
        const float* __restrict__ in, const float* __restrict__ wgt,
        const float* __restrict__ bias, float* __restrict__ ws) {
    __shared__ float xs[6 * 67 + 8];   // stride 67: odd stride -> 2-way-max bank aliasing (free)
    __shared__ float wb[64 * 12];      // per-ci weights, stride 12 floats = 48B (16B aligned)
    float* ybuf = ws + WS_Y;

    const int tid = threadIdx.x;
    const int b = blockIdx.y;
    const int ht = blockIdx.x >> 2;          // 0..63 -> h0 = ht*4
    const int wt = blockIdx.x & 3;           // 0..3  -> w0 = wt*64
    const int h0 = ht * 4, w0 = wt * 64;
    const int wv = tid >> 6, lane = tid & 63;
    const int cobase = wv * 16;
    const int prow = lane >> 4;              // 0..3
    const int pcol = (lane & 15) << 2;       // 0..60

    float acc[16][4];
    #pragma unroll
    for (int i = 0; i < 16; ++i)
        #pragma unroll
        for (int k = 0; k < 4; ++k) acc[i][k] = 0.f;

    for (int ci = 0; ci < 64; ++ci) {
        __syncthreads();
        // stage input tile 6 rows x 66 cols (zero padding at image border)
        for (int i = tid; i < 6 * 66; i += 256) {
            int r = i / 66, cc = i - r * 66;
            int gh = h0 - 1 + r, gw = w0 - 1 + cc;
            float v = 0.f;
            if (gh >= 0 && gh < HH && gw >= 0 && gw < WW)
                v = in[(((b << 6) + ci) << 16) + (gh << 8) + gw];
            xs[r * 67 + cc] = v;
        }
        // stage weights for this ci: 64 co x 9 taps, padded stride 12
        for (int i = tid; i < 576; i += 256) {
            int co = i / 9, tap = i - co * 9;
            wb[co * 12 + tap] = wgt[(((co << 6) + ci) * 9) + tap];
        }
        __syncthreads();

        // per-thread receptive field: 3 rows x 6 cols
        float xr[3][6];
        #pragma unroll
        for (int dh = 0; dh < 3; ++dh)
            #pragma unroll
            for (int dx = 0; dx < 6; ++dx)
                xr[dh][dx] = xs[(prow + dh) * 67 + pcol + dx];

        #pragma unroll
        for (int co16 = 0; co16 < 16; ++co16) {
            const float4* wp = (const float4*)&wb[(cobase + co16) * 12];
            float4 wA = wp[0];
            float4 wB = wp[1];
            float w8 = wb[(cobase + co16) * 12 + 8];
            #pragma unroll
            for (int k = 0; k < 4; ++k) {
                float s = acc[co16][k];
                s = fmaf(wA.x, xr[0][k + 0], s);
                s = fmaf(wA.y, xr[0][k + 1], s);
                s = fmaf(wA.z, xr[0][k + 2], s);
                s = fmaf(wA.w, xr[1][k + 0], s);
                s = fmaf(wB.x, xr[1][k + 1], s);
                s = fmaf(wB.y, xr[1][k + 2], s);
                s = fmaf(wB.z, xr[2][k + 0], s);
                s = fmaf(wB.w, xr[2][k + 1], s);
                s = fmaf(w8,   xr[2][k + 2], s);
                acc[co16][k] = s;
            }
        }
    }

    const int gh = h0 + prow;
    #pragma unroll
    for (int co16 = 0; co16 < 16; ++co16) {
        int co = cobase + co16;
        float bs = bias[co];
        float4 v = make_float4(acc[co16][0] + bs, acc[co16][1] + bs,
                               acc[co16][2] + bs, acc[co16][3] + bs);
        *(float4*)&ybuf[(((b << 6) + co) << 16) + (gh << 8) + w0 + pcol] = v;
        float s  = v.x + v.y + v.z + v.w;
        float s2 = v.x * v.x + v.y * v.y + v.z * v.z + v.w * v.w;
        #pragma unroll
        for (int off = 32; off; off >>= 1) {
            s  += __shfl_xor(s,  off, 64);
            s2 += __shfl_xor(s2, off, 64);
        }
        if (lane == 0) {
            atomicAdd(&ws[WS_SUM + co], s);
            atomicAdd(&ws[WS_SUMSQ + co], s2);
        }
    }
}

// Finalize BN affine per channel; build K = fx (*) fx + fy (*) fy (5x5); copy fx, fy.
__global__ void finalize(const float* __restrict__ gamma, const float* __restrict__ beta,
                         const float* __restrict__ fx, const float* __restrict__ fy,
                         float* ws) {
    int t = threadIdx.x;
    const float invN = 1.f / (float)(BATCH * HH * WW);
    if (t < 64) {
        float m = ws[WS_SUM + t] * invN;
        float v = ws[WS_SUMSQ + t] * invN - m * m;
        float rstd = rsqrtf(v + BN_EPS);
        float a = gamma[t] * rstd;
        ws[WS_A + t] = a;
        ws[WS_B + t] = beta[t] - m * a;
    }
    if (t < 25) {
        int c5 = t / 5, d = t % 5;
        float s = 0.f;
        for (int i = 0; i < 3; ++i)
            for (int j = 0; j < 3; ++j) {
                int i2 = c5 - i, j2 = d - j;
                if (i2 >= 0 && i2 < 3 && j2 >= 0 && j2 < 3)
                    s += fx[i * 3 + j] * fx[i2 * 3 + j2] + fy[i * 3 + j] * fy[i2 * 3 + j2];
            }
        ws[WS_COEF + t] = s;
    }
    if (t >= 32 && t < 41) ws[WS_COEF + 25 + (t - 32)] = fx[t - 32];
    if (t >= 48 && t < 57) ws[WS_COEF + 34 + (t - 48)] = fy[t - 48];
}

// Per (b,c): relu(y*a+b) on load (circular 20x68 tile), then
// curv = K(*)x + gx^2 + gy^2 - 2 gx gy + x   (circular convs, one-sided support)
__global__ __launch_bounds__(256) void curvature(
        const float* __restrict__ ws, float* __restrict__ out) {
    __shared__ float xs[20 * 69 + 8];  // stride 69 -> 2-way-max bank aliasing
    __shared__ float cf[43];
    const float* ybuf = ws + WS_Y;
    const int tid = threadIdx.x;
    const int c = blockIdx.y;
    const int b = blockIdx.z;
    const int tile = blockIdx.x;            // 0..63
    const int h0 = (tile >> 2) * 16;
    const int w0 = (tile & 3) * 64;
    const float a  = ws[WS_A + c];
    const float bb = ws[WS_B + c];
    const int chbase = ((b << 6) + c) << 16;

    if (tid < 43) cf[tid] = ws[WS_COEF + tid];
    for (int i = tid; i < 20 * 68; i += 256) {
        int r = i / 68, cc = i - r * 68;
        int gh = (h0 - 4 + r) & 255;
        int gw = (w0 - 4 + cc) & 255;
        float yv = ybuf[chbase + (gh << 8) + gw];
        xs[r * 69 + cc] = fmaxf(fmaf(yv, a, bb), 0.f);
    }
    __syncthreads();

    const int row = tid >> 4;                // 0..15
    const int c4 = (tid & 15) << 2;          // 0..60
    float res[4];
    #pragma unroll
    for (int k = 0; k < 4; ++k) {
        const int R = row + 4, Cc = c4 + 4 + k;
        float gx = 0.f, gy = 0.f, kc = 0.f;
        #pragma unroll
        for (int a2 = 0; a2 < 3; ++a2)
            #pragma unroll
            for (int b2 = 0; b2 < 3; ++b2) {
                float xv = xs[(R - a2) * 69 + Cc - b2];
                gx = fmaf(cf[25 + a2 * 3 + b2], xv, gx);
                gy = fmaf(cf[34 + a2 * 3 + b2], xv, gy);
            }
        #pragma unroll
        for (int c5 = 0; c5 < 5; ++c5)
            #pragma unroll
            for (int d = 0; d < 5; ++d)
                kc = fmaf(cf[c5 * 5 + d], xs[(R - c5) * 69 + Cc - d], kc);
        float xc = xs[R * 69 + Cc];
        res[k] = kc + gx * gx + gy * gy - 2.f * gx * gy + xc;
    }
    *(float4*)&out[chbase + ((h0 + row) << 8) + w0 + c4] =
        make_float4(res[0], res[1], res[2], res[3]);
}

extern "C" void kernel_launch(void* const* d_in, const int* in_sizes, int n_in,
                              void* d_out, int out_size, void* d_ws, size_t ws_size,
                              hipStream_t stream) {
    const float* in    = (const float*)d_in[0];
    const float* wgt   = (const float*)d_in[1];
    const float* bias  = (const float*)d_in[2];
    const float* gamma = (const float*)d_in[3];
    const float* beta  = (const float*)d_in[4];
    const float* fx    = (const float*)d_in[5];
    const float* fy    = (const float*)d_in[6];
    float* out = (float*)d_out;
    float* ws  = (float*)d_ws;

    hipLaunchKernelGGL(init_stats, dim3(1), dim3(128), 0, stream, ws);
    hipLaunchKernelGGL(conv_bn_stats, dim3(256, 8), dim3(256), 0, stream,
                       in, wgt, bias, ws);
    hipLaunchKernelGGL(finalize, dim3(1), dim3(64), 0, stream,
                       gamma, beta, fx, fy, ws);
    hipLaunchKernelGGL(curvature, dim3(64, 64, 8), dim3(256), 0, stream, ws, out);
}

// Round 2
// 502.698 us; speedup vs baseline: 2.7673x; 2.7673x over previous
//
#include <hip/hip_runtime.h>

#define BATCH 8
#define HH 256
#define WW 256
#define BN_EPS 1e-5f

// ws float-offsets for small area
#define WS_A 128
#define WS_B 192
#define WS_COEF 256
// ws byte-offsets for big buffers
#define WA_OFF   4096ull       // 73728 B: A-frag-ready weights (bf16, 16B/lane entries)
#define PART_OFF 131072ull     // 2 x 64*8192 floats = 4 MB (sum, sumsq partials)
#define XT_OFF   4456448ull    // padded NHWC bf16 x: 8 * 258 * (258*8 blocks) * 16 B = 68.16 MB
#define Y_OFF    73400320ull   // y bf16 NCHW: 67.1 MB

typedef __attribute__((ext_vector_type(8))) short bf16x8;
typedef __attribute__((ext_vector_type(4))) float f32x4;

__device__ __forceinline__ unsigned short f2bf(float f) {
    unsigned u = __float_as_uint(f);
    u += 0x7fffu + ((u >> 16) & 1u);          // RNE
    return (unsigned short)(u >> 16);
}
__device__ __forceinline__ float bf2f(unsigned short s) {
    return __uint_as_float(((unsigned)s) << 16);
}

// x NCHW fp32 -> padded (258x258) NHWC bf16, ci in XOR-swizzled 16B blocks.
// block index within row: col*8 + (kb ^ (col&7)), kb = ci/8. One block per (b,row).
__global__ __launch_bounds__(256) void transpose_x(const float* __restrict__ in,
                                                   int4* __restrict__ xt) {
    const int row = blockIdx.x, b = blockIdx.y;
    const int tid = threadIdx.x;
    const int cg = tid & 63, kb0 = tid >> 6;
    const int base_in = (b << 22) + (row << 8);
    const int rowblk = (b * 258 + row + 1) * 2064;   // 2064 = 258 cols * 8 blocks
    for (int kb = kb0; kb < 8; kb += 4) {
        float v[8][4];
        #pragma unroll
        for (int j = 0; j < 8; ++j) {
            float4 f = *(const float4*)&in[base_in + ((kb * 8 + j) << 16) + cg * 4];
            v[j][0] = f.x; v[j][1] = f.y; v[j][2] = f.z; v[j][3] = f.w;
        }
        #pragma unroll
        for (int cc = 0; cc < 4; ++cc) {
            int col = cg * 4 + cc + 1;               // padded col
            union { short s[8]; int4 q; } u;
            #pragma unroll
            for (int j = 0; j < 8; ++j) u.s[j] = (short)f2bf(v[j][cc]);
            xt[rowblk + col * 8 + (kb ^ (col & 7))] = u.q;
        }
    }
}

// Zero the pad border of xt: rows 0/257 fully, cols 0/257 for rows 1..256. Per b: 8224 blocks.
__global__ void pad_xt(int4* __restrict__ xt) {
    int i = blockIdx.x * 256 + threadIdx.x;
    if (i >= 8 * 8224) return;
    int b = i / 8224, r = i - b * 8224;
    int blk;
    if (r < 4128) {
        int row = (r < 2064) ? 0 : 257;
        int off = (r < 2064) ? r : r - 2064;
        blk = (b * 258 + row) * 2064 + off;
    } else {
        int r2 = r - 4128;
        int row = 1 + (r2 >> 4);
        int s = r2 & 15;
        int col = (s < 8) ? 0 : 257;
        blk = (b * 258 + row) * 2064 + col * 8 + (s & 7);
    }
    xt[blk] = make_int4(0, 0, 0, 0);
}

// Weights -> A-frag-ready: entry e = f*64+lane, f = 8t+4ks+mt.
// lane holds W[co=16mt+(lane&15)][ci = ks*32 + (lane>>4)*8 + j], j=0..7, bf16.
__global__ void transpose_w(const float* __restrict__ wgt, int4* __restrict__ wA) {
    int tid = threadIdx.x;
    for (int e = tid; e < 4608; e += 256) {
        int le = e & 63, f = e >> 6;
        int mt = f & 3, ks = (f >> 2) & 1, t = f >> 3;
        int co = 16 * mt + (le & 15), ci0 = ks * 32 + (le >> 4) * 8;
        union { short s[8]; int4 q; } u;
        #pragma unroll
        for (int j = 0; j < 8; ++j)
            u.s[j] = (short)f2bf(wgt[(co * 64 + ci0 + j) * 9 + t]);
        wA[e] = u.q;
    }
}

// MFMA conv: block = 4 out rows x 64 cols, all 64 co. Wave w -> out row w, tile 64co x 64px.
// acc[mt][nt]: mfma_f32_16x16x32_bf16, 9 taps x 2 ksteps. A from global (L2-hot), B from LDS.
__global__ __launch_bounds__(256, 2) void conv_mfma(
        const int4* __restrict__ xt, const int4* __restrict__ wA,
        const float* __restrict__ bias, unsigned short* __restrict__ y,
        float* __restrict__ part) {
    __shared__ int4 xs[6 * 576];   // 6 rows x 72 cols x 8 blocks = 55296 B
    const int tid = threadIdx.x, lane = tid & 63, wv = tid >> 6;
    const int b = blockIdx.y;
    const int ht = blockIdx.x >> 2, wt = blockIdx.x & 3;
    const int h0 = ht * 4, w0 = wt * 64;
    const int bid = blockIdx.y * 256 + blockIdx.x;

    // stage 6 rows x 576 blocks (cols w0..w0+71 padded coords; only LC<=65 is consumed)
    for (int ch = wv; ch < 54; ch += 4) {
        int row = ch / 9, seg = ch - row * 9;
        xs[row * 576 + seg * 64 + lane] =
            xt[(b * 258 + h0 + row) * 2064 + w0 * 8 + seg * 64 + lane];
    }
    __syncthreads();

    const int q = lane >> 4, n = lane & 15;
    const int r = wv;
    f32x4 acc[4][4] = {};

    #pragma unroll
    for (int t = 0; t < 9; ++t) {
        const int kh = t / 3, kw = t - 3 * (t / 3);
        #pragma unroll
        for (int ks = 0; ks < 2; ++ks) {
            bf16x8 af[4];
            #pragma unroll
            for (int mt = 0; mt < 4; ++mt) {
                int4 v = wA[(8 * t + 4 * ks + mt) * 64 + lane];
                af[mt] = *(bf16x8*)&v;
            }
            bf16x8 bfr[4];
            #pragma unroll
            for (int nt = 0; nt < 4; ++nt) {
                int LC = 16 * nt + n + kw;
                int vq = (ks * 4 + q) ^ (LC & 7);
                bfr[nt] = *(const bf16x8*)&xs[(r + kh) * 576 + LC * 8 + vq];
            }
            #pragma unroll
            for (int mt = 0; mt < 4; ++mt)
                #pragma unroll
                for (int nt = 0; nt < 4; ++nt)
                    acc[mt][nt] = __builtin_amdgcn_mfma_f32_16x16x32_bf16(
                        af[mt], bfr[nt], acc[mt][nt], 0, 0, 0);
        }
    }

    // epilogue: +bias, y bf16 store, per-co row sums -> per-(block,wave) partials
    const int gr = h0 + r;
    #pragma unroll
    for (int mt = 0; mt < 4; ++mt) {
        #pragma unroll
        for (int rg = 0; rg < 4; ++rg) {
            int co = 16 * mt + 4 * q + rg;
            float bs = bias[co];
            float s1 = 0.f, s2 = 0.f;
            size_t ybase = ((size_t)(b * 64 + co) << 16) + (gr << 8) + w0 + n;
            #pragma unroll
            for (int nt = 0; nt < 4; ++nt) {
                float yv = acc[mt][nt][rg] + bs;
                y[ybase + 16 * nt] = f2bf(yv);
                s1 += yv; s2 += yv * yv;
            }
            #pragma unroll
            for (int m = 1; m < 16; m <<= 1) {
                s1 += __shfl_xor(s1, m, 64);
                s2 += __shfl_xor(s2, m, 64);
            }
            if (n == 0) {
                part[co * 8192 + bid * 4 + wv] = s1;
                part[64 * 8192 + co * 8192 + bid * 4 + wv] = s2;
            }
        }
    }
}

// blocks 0..63: reduce partials -> BN affine a,b. block 64: K = fx*fx + fy*fy (5x5), copy fx,fy.
__global__ void finalize_stats(const float* __restrict__ part,
                               const float* __restrict__ gamma, const float* __restrict__ beta,
                               const float* __restrict__ fx, const float* __restrict__ fy,
                               float* ws) {
    __shared__ float red[512];
    int t = threadIdx.x, co = blockIdx.x;
    if (co < 64) {
        float s1 = 0.f, s2 = 0.f;
        for (int i = t; i < 8192; i += 256) {
            s1 += part[co * 8192 + i];
            s2 += part[64 * 8192 + co * 8192 + i];
        }
        red[t] = s1; red[256 + t] = s2;
        __syncthreads();
        for (int st = 128; st; st >>= 1) {
            if (t < st) { red[t] += red[t + st]; red[256 + t] += red[256 + t + st]; }
            __syncthreads();
        }
        if (t == 0) {
            const float invN = 1.f / 524288.f;
            float m = red[0] * invN;
            float v = red[256] * invN - m * m;
            float a = gamma[co] * rsqrtf(v + BN_EPS);
            ws[WS_A + co] = a;
            ws[WS_B + co] = beta[co] - m * a;
        }
    } else {
        if (t < 25) {
            int c5 = t / 5, d = t % 5;
            float s = 0.f;
            for (int i = 0; i < 3; ++i)
                for (int j = 0; j < 3; ++j) {
                    int i2 = c5 - i, j2 = d - j;
                    if (i2 >= 0 && i2 < 3 && j2 >= 0 && j2 < 3)
                        s += fx[i * 3 + j] * fx[i2 * 3 + j2] + fy[i * 3 + j] * fy[i2 * 3 + j2];
                }
            ws[WS_COEF + t] = s;
        }
        if (t >= 32 && t < 41) ws[WS_COEF + 25 + (t - 32)] = fx[t - 32];
        if (t >= 48 && t < 57) ws[WS_COEF + 34 + (t - 48)] = fy[t - 48];
    }
}

// curvature: per (b,c, 64x64 tile): relu(y*a+b) staged circularly (halo 4), then per-thread
// 4x4 outputs from an 8x8 register patch: curv = K(*)x + gx^2+gy^2-2gxgy + x.
__global__ __launch_bounds__(256) void curvature2(const float* __restrict__ ws,
        const unsigned short* __restrict__ ybuf, float* __restrict__ out) {
    __shared__ float xs[68 * 68];     // stride 68 (16B-aligned rows)
    __shared__ float cf[43];
    const int tid = threadIdx.x;
    const int c = blockIdx.y, b = blockIdx.z;
    const int h0 = (blockIdx.x >> 2) * 64, w0 = (blockIdx.x & 3) * 64;
    const float a = ws[WS_A + c], bb = ws[WS_B + c];
    const size_t ch = ((size_t)(b * 64 + c)) << 16;
    if (tid < 43) cf[tid] = ws[WS_COEF + tid];
    for (int i = tid; i < 68 * 68; i += 256) {
        int rr = i / 68, cc = i - rr * 68;
        int gh = (h0 - 4 + rr) & 255, gw = (w0 - 4 + cc) & 255;
        float yv = bf2f(ybuf[ch + (gh << 8) + gw]);
        xs[i] = fmaxf(fmaf(yv, a, bb), 0.f);
    }
    __syncthreads();

    const int tx = tid & 15, ty = tid >> 4;
    const int R0 = ty * 4, C0 = tx * 4;
    float p[8][8];
    #pragma unroll
    for (int r8 = 0; r8 < 8; ++r8) {
        float4 u0 = *(float4*)&xs[(R0 + r8) * 68 + C0];
        float4 u1 = *(float4*)&xs[(R0 + r8) * 68 + C0 + 4];
        p[r8][0] = u0.x; p[r8][1] = u0.y; p[r8][2] = u0.z; p[r8][3] = u0.w;
        p[r8][4] = u1.x; p[r8][5] = u1.y; p[r8][6] = u1.z; p[r8][7] = u1.w;
    }
    #pragma unroll
    for (int rr = 0; rr < 4; ++rr) {
        float res[4];
        #pragma unroll
        for (int cc = 0; cc < 4; ++cc) {
            float gx = 0.f, gy = 0.f, kc = 0.f;
            #pragma unroll
            for (int a2 = 0; a2 < 3; ++a2)
                #pragma unroll
                for (int b2 = 0; b2 < 3; ++b2) {
                    float xv = p[rr + 4 - a2][cc + 4 - b2];
                    gx = fmaf(cf[25 + a2 * 3 + b2], xv, gx);
                    gy = fmaf(cf[34 + a2 * 3 + b2], xv, gy);
                }
            #pragma unroll
            for (int c5 = 0; c5 < 5; ++c5)
                #pragma unroll
                for (int d = 0; d < 5; ++d)
                    kc = fmaf(cf[c5 * 5 + d], p[rr + 4 - c5][cc + 4 - d], kc);
            res[cc] = kc + gx * gx + gy * gy - 2.f * gx * gy + p[rr + 4][cc + 4];
        }
        *(float4*)&out[ch + ((size_t)(h0 + R0 + rr) << 8) + w0 + C0] =
            make_float4(res[0], res[1], res[2], res[3]);
    }
}

extern "C" void kernel_launch(void* const* d_in, const int* in_sizes, int n_in,
                              void* d_out, int out_size, void* d_ws, size_t ws_size,
                              hipStream_t stream) {
    const float* in    = (const float*)d_in[0];
    const float* wgt   = (const float*)d_in[1];
    const float* bias  = (const float*)d_in[2];
    const float* gamma = (const float*)d_in[3];
    const float* beta  = (const float*)d_in[4];
    const float* fx    = (const float*)d_in[5];
    const float* fy    = (const float*)d_in[6];
    float* out = (float*)d_out;

    float* wsf = (float*)d_ws;
    int4*  wA   = (int4*)((char*)d_ws + WA_OFF);
    float* part = (float*)((char*)d_ws + PART_OFF);
    int4*  xt   = (int4*)((char*)d_ws + XT_OFF);
    unsigned short* ybuf = (unsigned short*)((char*)d_ws + Y_OFF);

    hipLaunchKernelGGL(transpose_x, dim3(256, 8), dim3(256), 0, stream, in, xt);
    hipLaunchKernelGGL(pad_xt, dim3(257), dim3(256), 0, stream, xt);
    hipLaunchKernelGGL(transpose_w, dim3(1), dim3(256), 0, stream, wgt, wA);
    hipLaunchKernelGGL(conv_mfma, dim3(256, 8), dim3(256), 0, stream,
                       xt, wA, bias, ybuf, part);
    hipLaunchKernelGGL(finalize_stats, dim3(65), dim3(256), 0, stream,
                       part, gamma, beta, fx, fy, wsf);
    hipLaunchKernelGGL(curvature2, dim3(16, 64, 8), dim3(256), 0, stream,
                       wsf, ybuf, out);
}